// Round 4
// baseline (379.384 us; speedup 1.0000x reference)
//
#include <hip/hip_runtime.h>
#include <cstdint>
#include <cstddef>

#define Bn 32
#define Pn 64
#define Ln 64
#define Vn 32000
// float4 row length = 8000, split: waves 1..3 take 2368 each, wave 0 takes 896
#define W13_CHUNK 2368
#define W0_BASE   7104
#define W0_CHUNK  896

// ---------------------------------------------------------------------------
// Fully fused EDOCD loss. One block (256 thr) per (b,i) row of outputs.
//
// Waves 1..3: stream float4[0 .. 7104) of the row (37 loads/lane, 4 accs).
// Wave 0: mask decode + anti-diagonal edit-distance DP (lane = row, 127
//   steps of 2 shfl_up + fmin) + row-i min/argmin/token-dedup + S_opt
//   gather, THEN streams float4[7104 .. 8000) (14 loads/lane) — its smaller
//   share compensates the ~5 us serial DP prefix so all waves finish
//   together and every lane issues HBM loads.
//
// Closed form (q has exactly two values per row; softmax is shift-invariant):
//   m = popcount(M); p_hi = 1/(m + (V-m)e^-1); p_lo = e^-1 p_hi
//   kl = m p_hi ln p_hi + (V-m) p_lo ln p_lo - [p_lo S_all + (p_hi-p_lo) S_opt]
//   contribution = kl * mask[b,i]/(wsum[b]+eps) / n_nonempty  (atomicAdd)
// ---------------------------------------------------------------------------
__global__ __launch_bounds__(256) void edocd_fused(
    const float* __restrict__ outputs,   // (B,P,V) f32
    const int* __restrict__ syms,        // (B,P)
    const int* __restrict__ targets,     // (B,L)
    const void* __restrict__ maskp,      // (B,L) bool (u8 or i32)
    float* __restrict__ d_out)
{
    const int id   = blockIdx.x;         // b*P + i
    const int b    = id >> 6;
    const int i    = id & 63;
    const int tid  = threadIdx.x;
    const int wave = tid >> 6;
    const int lane = tid & 63;

    __shared__ float dist[Pn * Ln];      // 16 KB, wave-0 private
    __shared__ int   tg[Ln];
    __shared__ float red[4];

    const float4* __restrict__ row4 =
        (const float4*)(outputs + (size_t)id * Vn);

    if (wave != 0) {
        // ---- contiguous per-wave region, lane-strided, 4 accumulators ----
        int idx = (wave - 1) * W13_CHUNK + lane;
        float p0 = 0.0f, p1 = 0.0f, p2 = 0.0f, p3 = 0.0f;
        #pragma unroll
        for (int it = 0; it < 9; ++it, idx += 256) {      // 9*4 = 36 loads
            const float4 a = row4[idx];
            const float4 c = row4[idx + 64];
            const float4 e = row4[idx + 128];
            const float4 g = row4[idx + 192];
            p0 += (a.x + a.y) + (a.z + a.w);
            p1 += (c.x + c.y) + (c.z + c.w);
            p2 += (e.x + e.y) + (e.z + e.w);
            p3 += (g.x + g.y) + (g.z + g.w);
        }
        {                                                  // 37th load
            const float4 a = row4[idx];
            p0 += (a.x + a.y) + (a.z + a.w);
        }
        float partial = (p0 + p1) + (p2 + p3);
        #pragma unroll
        for (int d = 32; d >= 1; d >>= 1) partial += __shfl_xor(partial, d);
        if (lane == 0) red[wave] = partial;
        __syncthreads();
        return;
    }

    // ======================= wave 0 ======================================
    tg[lane] = targets[b * Ln + lane];

    // mask layout detection: lengths >= 32 so mask[0][1] is true.
    // u8 layout: byte 1 == 1; i32 layout: byte 1 = high byte of elem 0 == 0.
    const unsigned char* m8 = (const unsigned char*)maskp;
    const bool is_u8 = (m8[1] != 0);
    const bool mj = is_u8 ? (m8[b * Ln + lane] != 0)
                          : (((const int*)maskp)[b * Ln + lane] != 0);
    const unsigned long long mbits = __ballot(mj);
    const float ws = (float)__popcll(mbits);

    // n_nonempty: mask rows are prefix-true, so row bb nonempty <=> mask[bb][0]
    bool nz = false;
    if (lane < Bn)
        nz = is_u8 ? (m8[lane * Ln] != 0)
                   : (((const int*)maskp)[lane * Ln] != 0);
    const float nn = (float)__popcll(__ballot(nz)) + 1e-13f;

    // ---- anti-diagonal DP: lane = row ------------------------------------
    const int sym = (lane >= 1) ? syms[b * Pn + lane - 1] : -1;
    float a1 = 0.0f, a2 = 0.0f;
    for (int k = 0; k < Pn + Ln - 1; ++k) {
        const float up = __shfl_up(a1, 1);    // d[r-1][j]
        const float ud = __shfl_up(a2, 1);    // d[r-1][j-1]
        const int j = k - lane;
        float val = a1;
        if (j >= 0 && j < Ln) {
            if (lane == 0)   val = (float)j;
            else if (j == 0) val = (float)lane;
            else {
                const float neq = (sym != tg[j - 1]) ? 1.0f : 0.0f;
                val = fminf(ud + neq, fminf(up, a1) + 1.0f);
            }
            dist[lane * Ln + j] = val;
        }
        a2 = a1;
        a1 = val;
    }

    // ---- row i: min, argmin ballot, token dedup --------------------------
    const float cur = dist[i * Ln + lane];
    float mn = mj ? cur : INFINITY;
    #pragma unroll
    for (int d = 32; d >= 1; d >>= 1) mn = fminf(mn, __shfl_xor(mn, d));

    bool opt = mj && (cur == mn);
    const unsigned long long bits = __ballot(opt);
    if (opt) {
        const int tself = tg[lane];
        unsigned long long e =
            bits & ((lane == 0) ? 0ull : (~0ull >> (64 - lane)));
        while (e) {
            const int kk = __ffsll((unsigned long long)e) - 1;
            e &= e - 1;
            if (tg[kk] == tself) { opt = false; break; }
        }
    }
    const unsigned long long M = __ballot(opt);

    // ---- S_opt gather (scattered; overlaps wave-0 streaming below) -------
    float so = 0.0f;
    if ((M >> lane) & 1ull)
        so = outputs[(size_t)id * Vn + tg[lane]];

    // ---- wave-0 streaming share: float4[7104 .. 8000), 14 loads/lane -----
    {
        int idx = W0_BASE + lane;
        float q0 = 0.0f, q1 = 0.0f;
        #pragma unroll
        for (int it = 0; it < 7; ++it, idx += 128) {       // 7*2 = 14 loads
            const float4 a = row4[idx];
            const float4 c = row4[idx + 64];
            q0 += (a.x + a.y) + (a.z + a.w);
            q1 += (c.x + c.y) + (c.z + c.w);
        }
        float partial = q0 + q1;
        #pragma unroll
        for (int d = 32; d >= 1; d >>= 1) partial += __shfl_xor(partial, d);
        if (lane == 0) red[0] = partial;
    }

    #pragma unroll
    for (int d = 32; d >= 1; d >>= 1) so += __shfl_xor(so, d);

    __syncthreads();                     // red[] complete

    if (lane == 0) {
        const bool mi = (mbits >> i) & 1ull;
        if (mi) {
            const float w     = 1.0f / (ws + 1e-13f);
            const float S_all = (red[0] + red[1]) + (red[2] + red[3]);
            const float m     = (float)__popcll(M);

            const float einv = 0.36787944117144233f;   // exp(-1)
            const float D    = m + ((float)Vn - m) * einv;
            const float p_hi = 1.0f / D;
            const float p_lo = einv / D;

            const float plogp = m * p_hi * logf(p_hi)
                              + ((float)Vn - m) * p_lo * logf(p_lo);
            const float cross = p_lo * S_all + (p_hi - p_lo) * so;
            const float kl = plogp - cross;

            atomicAdd(d_out, kl * w / nn);
        }
    }
}

// ---------------------------------------------------------------------------
extern "C" void kernel_launch(void* const* d_in, const int* in_sizes, int n_in,
                              void* d_out, int out_size, void* d_ws, size_t ws_size,
                              hipStream_t stream)
{
    const float* outputs = (const float*)d_in[0];
    const int*   syms    = (const int*)d_in[1];
    const int*   targets = (const int*)d_in[2];
    const void*  mask    = d_in[3];

    hipMemsetAsync(d_out, 0, sizeof(float), stream);   // capture-legal
    edocd_fused<<<Bn * Pn, 256, 0, stream>>>(outputs, syms, targets, mask,
                                             (float*)d_out);
}

// Round 5
// 363.145 us; speedup vs baseline: 1.0447x; 1.0447x over previous
//
#include <hip/hip_runtime.h>
#include <cstdint>
#include <cstddef>

#define Bn 32
#define Pn 64
#define Ln 64
#define Vn 32000

// ---------------------------------------------------------------------------
// Fully fused EDOCD loss. One block (256 thr) per (b,i) row of outputs.
// [R4 note: this is the R3-measured-best structure. R4's experiment of giving
//  wave 0 a streaming share after its DP regressed +16 us — wave 0's serial
//  DP chain + tail loads became the block critical path, while the 3
//  streaming waves already saturated per-CU HBM issue. Keep wave 0
//  compute-only.]
//
// Waves 1..3 (192 thr): stream the V=32000-float row (float4, 2-way unroll)
//   for S_all = sum_v outputs[b,i,v]   -- the only HBM-heavy work (262 MB).
//
// Wave 0 (concurrently, fully hidden under the streaming):
//   - mask decode (u8 vs i32 runtime-detected), wsum[b], n_nonempty
//   - anti-diagonal edit-distance DP for batch b (lane = row, 127 steps of
//     2 shfl_up + fmin)
//   - row-i min + argmin ballot + first-occurrence token dedup -> mask M
//   - S_opt = sum of row[targets[b,j]] over set bits of M
//
// Closed form (q has exactly two values per row; softmax is shift-invariant):
//   m = popcount(M); p_hi = 1/(m + (V-m)e^-1); p_lo = e^-1 p_hi
//   kl = m p_hi ln p_hi + (V-m) p_lo ln p_lo - [p_lo S_all + (p_hi-p_lo) S_opt]
//   contribution = kl * mask[b,i]/(wsum[b]+eps) / n_nonempty  (atomicAdd)
// ---------------------------------------------------------------------------
__global__ __launch_bounds__(256) void edocd_fused(
    const float* __restrict__ outputs,   // (B,P,V) f32
    const int* __restrict__ syms,        // (B,P)
    const int* __restrict__ targets,     // (B,L)
    const void* __restrict__ maskp,      // (B,L) bool (u8 or i32)
    float* __restrict__ d_out)
{
    const int id   = blockIdx.x;         // b*P + i
    const int b    = id >> 6;
    const int i    = id & 63;
    const int tid  = threadIdx.x;
    const int wave = tid >> 6;
    const int lane = tid & 63;

    __shared__ float dist[Pn * Ln];      // 16 KB, wave-0 private
    __shared__ int   tg[Ln];
    __shared__ float red[3];             // row-sum partials from waves 1..3

    if (wave != 0) {
        // ---- streaming row sum over 8000 float4 with 192 threads ---------
        const float4* __restrict__ row4 =
            (const float4*)(outputs + (size_t)id * Vn);
        const int t = tid - 64;
        float p0 = 0.0f, p1 = 0.0f;
        int idx = t;
        for (; idx + 192 < Vn / 4; idx += 384) {
            const float4 a = row4[idx];
            const float4 c = row4[idx + 192];
            p0 += (a.x + a.y) + (a.z + a.w);
            p1 += (c.x + c.y) + (c.z + c.w);
        }
        if (idx < Vn / 4) {
            const float4 a = row4[idx];
            p0 += (a.x + a.y) + (a.z + a.w);
        }
        float partial = p0 + p1;
        #pragma unroll
        for (int d = 32; d >= 1; d >>= 1) partial += __shfl_xor(partial, d);
        if (lane == 0) red[wave - 1] = partial;
        __syncthreads();
        return;
    }

    // ======================= wave 0 ======================================
    const float* __restrict__ row = outputs + (size_t)id * Vn;

    tg[lane] = targets[b * Ln + lane];

    // mask layout detection: lengths >= 32 so mask[0][1] is true.
    // u8 layout: byte 1 == 1; i32 layout: byte 1 = high byte of elem 0 == 0.
    const unsigned char* m8 = (const unsigned char*)maskp;
    const bool is_u8 = (m8[1] != 0);
    const bool mj = is_u8 ? (m8[b * Ln + lane] != 0)
                          : (((const int*)maskp)[b * Ln + lane] != 0);
    const unsigned long long mbits = __ballot(mj);
    const float ws = (float)__popcll(mbits);

    // n_nonempty: mask rows are prefix-true, so row bb nonempty <=> mask[bb][0]
    bool nz = false;
    if (lane < Bn)
        nz = is_u8 ? (m8[lane * Ln] != 0)
                   : (((const int*)maskp)[lane * Ln] != 0);
    const float nn = (float)__popcll(__ballot(nz)) + 1e-13f;

    // ---- anti-diagonal DP: lane = row ------------------------------------
    const int sym = (lane >= 1) ? syms[b * Pn + lane - 1] : -1;
    float a1 = 0.0f, a2 = 0.0f;
    for (int k = 0; k < Pn + Ln - 1; ++k) {
        const float up = __shfl_up(a1, 1);    // d[r-1][j]
        const float ud = __shfl_up(a2, 1);    // d[r-1][j-1]
        const int j = k - lane;
        float val = a1;
        if (j >= 0 && j < Ln) {
            if (lane == 0)   val = (float)j;
            else if (j == 0) val = (float)lane;
            else {
                const float neq = (sym != tg[j - 1]) ? 1.0f : 0.0f;
                val = fminf(ud + neq, fminf(up, a1) + 1.0f);
            }
            dist[lane * Ln + j] = val;
        }
        a2 = a1;
        a1 = val;
    }

    // ---- row i: min, argmin ballot, token dedup --------------------------
    const float cur = dist[i * Ln + lane];
    float mn = mj ? cur : INFINITY;
    #pragma unroll
    for (int d = 32; d >= 1; d >>= 1) mn = fminf(mn, __shfl_xor(mn, d));

    bool opt = mj && (cur == mn);
    const unsigned long long bits = __ballot(opt);
    if (opt) {
        const int tself = tg[lane];
        unsigned long long e =
            bits & ((lane == 0) ? 0ull : (~0ull >> (64 - lane)));
        while (e) {
            const int kk = __ffsll((unsigned long long)e) - 1;
            e &= e - 1;
            if (tg[kk] == tself) { opt = false; break; }
        }
    }
    const unsigned long long M = __ballot(opt);

    // ---- S_opt gather (row is L2-hot: waves 1-3 are streaming it) --------
    float so = 0.0f;
    if ((M >> lane) & 1ull) so = row[tg[lane]];
    #pragma unroll
    for (int d = 32; d >= 1; d >>= 1) so += __shfl_xor(so, d);

    __syncthreads();                     // red[] now valid

    if (lane == 0) {
        const bool mi = (mbits >> i) & 1ull;
        if (mi) {
            const float w     = 1.0f / (ws + 1e-13f);
            const float S_all = red[0] + red[1] + red[2];
            const float m     = (float)__popcll(M);

            const float einv = 0.36787944117144233f;   // exp(-1)
            const float D    = m + ((float)Vn - m) * einv;
            const float p_hi = 1.0f / D;
            const float p_lo = einv / D;

            const float plogp = m * p_hi * logf(p_hi)
                              + ((float)Vn - m) * p_lo * logf(p_lo);
            const float cross = p_lo * S_all + (p_hi - p_lo) * so;
            const float kl = plogp - cross;

            atomicAdd(d_out, kl * w / nn);
        }
    }
}

// ---------------------------------------------------------------------------
extern "C" void kernel_launch(void* const* d_in, const int* in_sizes, int n_in,
                              void* d_out, int out_size, void* d_ws, size_t ws_size,
                              hipStream_t stream)
{
    const float* outputs = (const float*)d_in[0];
    const int*   syms    = (const int*)d_in[1];
    const int*   targets = (const int*)d_in[2];
    const void*  mask    = d_in[3];

    hipMemsetAsync(d_out, 0, sizeof(float), stream);   // capture-legal
    edocd_fused<<<Bn * Pn, 256, 0, stream>>>(outputs, syms, targets, mask,
                                             (float*)d_out);
}